// Round 11
// baseline (536.841 us; speedup 1.0000x reference)
//
#include <hip/hip_runtime.h>
#include <hip/hip_bf16.h>
#include <math.h>

// Problem constants (from reference)
#define N_NODES   50000
#define N_EDGES   800000
#define EP        (N_EDGES + N_NODES)   // edges + self loops = 850000
#define IN_CH     128
#define HID       64
#define HEADS     4
#define F1        (HEADS * HID)         // 256
#define OUT_CH    10
#define NUM_GRAPHS 500
#define NEG_SLOPE 0.2f

typedef __attribute__((ext_vector_type(8))) short short8;   // 8 bf16 (4 VGPRs)
typedef __attribute__((ext_vector_type(4))) float floatx4;  // MFMA C/D

// bf16 pack/unpack helpers (RNE)
__device__ __forceinline__ unsigned short f2bf(float f) {
    unsigned int u = __float_as_uint(f);
    u += 0x7FFFu + ((u >> 16) & 1u);
    return (unsigned short)(u >> 16);
}
__device__ __forceinline__ unsigned int pack_bf2(float lo, float hi) {
    return (unsigned int)f2bf(lo) | ((unsigned int)f2bf(hi) << 16);
}
__device__ __forceinline__ float bf_lo(unsigned int u) { return __uint_as_float(u << 16); }
__device__ __forceinline__ float bf_hi(unsigned int u) { return __uint_as_float(u & 0xFFFF0000u); }
__device__ __forceinline__ float bf1(unsigned short h) { return __uint_as_float(((unsigned int)h) << 16); }

// ---------------------------------------------------------------------------
// CSR count (dst histogram) + W pack fused into one dispatch.
// ---------------------------------------------------------------------------
__global__ void csr_count_packw(const int* __restrict__ ei, int* __restrict__ deg,
                                const float* __restrict__ W1, unsigned short* __restrict__ W1p,
                                const float* __restrict__ W2, unsigned short* __restrict__ W2p)
{
    const int gid = blockIdx.x * blockDim.x + threadIdx.x;
    if (gid < EP) {
        const int dst = (gid < N_EDGES) ? ei[N_EDGES + gid] : gid - N_EDGES;
        atomicAdd(&deg[dst], 1);
    }
    if (gid < 4096) {                                        // W1: 16 nt x 4 kt x 64
        const int t = gid >> 8, kt = (gid >> 6) & 3, l = gid & 63;
        const int col = t * 16 + (l & 15);
        unsigned short* o = W1p + (size_t)((t * 4 + kt) * 64 + l) * 8;
        #pragma unroll
        for (int j = 0; j < 8; ++j) {
            const int k = kt * 32 + (l >> 4) * 8 + j;
            o[j] = f2bf(W1[k * F1 + col]);
        }
    } else if (gid < 6144) {                                 // W2: 4 nt x 8 kt x 64
        const int g2 = gid - 4096;
        const int t = g2 >> 9, kt = (g2 >> 6) & 7, l = g2 & 63;
        const int col = t * 16 + (l & 15);
        unsigned short* o = W2p + (size_t)((t * 8 + kt) * 64 + l) * 8;
        #pragma unroll
        for (int j = 0; j < 8; ++j) {
            const int k = kt * 32 + (l >> 4) * 8 + j;
            o[j] = f2bf(W2[k * HID + col]);
        }
    }
}

#define SCAN_B 196                       // ceil(50000 / 256)
__global__ __launch_bounds__(256) void csr_scan1(
    const int* __restrict__ deg, int* __restrict__ blocksum)
{
    const int b = blockIdx.x, t = threadIdx.x;
    const int i = b * 256 + t;
    __shared__ int sm[256];
    sm[t] = (i < N_NODES) ? deg[i] : 0;
    __syncthreads();
    for (int off = 128; off > 0; off >>= 1) {
        if (t < off) sm[t] += sm[t + off];
        __syncthreads();
    }
    if (t == 0) blocksum[b] = sm[0];
}
__global__ __launch_bounds__(256) void csr_scan2(
    const int* __restrict__ deg, const int* __restrict__ blocksum,
    int* __restrict__ rowptr, int* __restrict__ cursor)
{
    const int b = blockIdx.x, t = threadIdx.x;
    __shared__ int sm[256];
    sm[t] = (t < b) ? blocksum[t] : 0;     // b < SCAN_B <= 256
    __syncthreads();
    for (int off = 128; off > 0; off >>= 1) {
        if (t < off) sm[t] += sm[t + off];
        __syncthreads();
    }
    const int base = sm[0];
    __syncthreads();
    const int i = b * 256 + t;
    const int d = (i < N_NODES) ? deg[i] : 0;
    sm[t] = d;
    __syncthreads();
    for (int off = 1; off < 256; off <<= 1) {   // inclusive scan
        int u = (t >= off) ? sm[t - off] : 0;
        __syncthreads();
        if (t >= off) sm[t] += u;
        __syncthreads();
    }
    const int excl = base + sm[t] - d;
    if (i < N_NODES) { rowptr[i] = excl; cursor[i] = excl; }
    if (i == N_NODES - 1) rowptr[N_NODES] = excl + d;   // == EP
}

// scatter: src AND dst as ushort (N_NODES < 65536)
__global__ void csr_scatter(const int* __restrict__ ei, int* __restrict__ cursor,
                            unsigned short* __restrict__ csr_s,
                            unsigned short* __restrict__ csr_d)
{
    const int e = blockIdx.x * blockDim.x + threadIdx.x;
    if (e >= EP) return;
    int src, dst;
    if (e < N_EDGES) { src = ei[e]; dst = ei[N_EDGES + e]; }
    else             { src = dst = e - N_EDGES; }
    const int pos = atomicAdd(&cursor[dst], 1);
    csr_s[pos] = (unsigned short)src;
    csr_d[pos] = (unsigned short)dst;
}

// ---------------------------------------------------------------------------
// GEMM1 via MFMA + fused layer-1 logits (unchanged from round 9/10).
// ---------------------------------------------------------------------------
__global__ __launch_bounds__(256) void gemm1_mfma(
    const float* __restrict__ x, const short* __restrict__ W1p,
    const float* __restrict__ a_src1, const float* __restrict__ a_dst1,
    unsigned short* __restrict__ H1b,
    float* __restrict__ al_s1, float* __restrict__ al_d1)
{
    const int m0 = blockIdx.x * 16;
    const int w = threadIdx.x >> 6;
    const int l = threadIdx.x & 63;
    const int q = l >> 4, r = l & 15;
    floatx4 acc[4] = {};
    const float* arow = x + (size_t)(m0 + r) * IN_CH + q * 8;
    #pragma unroll
    for (int kt = 0; kt < 4; ++kt) {
        const float4 f0 = *(const float4*)(arow + kt * 32);
        const float4 f1 = *(const float4*)(arow + kt * 32 + 4);
        union { uint4 u; short8 s; } a;
        a.u = make_uint4(pack_bf2(f0.x, f0.y), pack_bf2(f0.z, f0.w),
                         pack_bf2(f1.x, f1.y), pack_bf2(f1.z, f1.w));
        #pragma unroll
        for (int t = 0; t < 4; ++t) {
            const int nt = w * 4 + t;
            const short8 b = *(const short8*)(W1p + (size_t)((nt * 4 + kt) * 64 + l) * 8);
            acc[t] = __builtin_amdgcn_mfma_f32_16x16x32_bf16(a.s, b, acc[t], 0, 0, 0);
        }
    }
    float ls[4] = {0.f, 0.f, 0.f, 0.f}, ld[4] = {0.f, 0.f, 0.f, 0.f};
    #pragma unroll
    for (int t = 0; t < 4; ++t) {
        const int col = (w * 4 + t) * 16 + r;
        const float as = a_src1[col], ad = a_dst1[col];
        #pragma unroll
        for (int reg = 0; reg < 4; ++reg) {
            H1b[(size_t)(m0 + q * 4 + reg) * F1 + col] = f2bf(acc[t][reg]);
            ls[reg] += acc[t][reg] * as;
            ld[reg] += acc[t][reg] * ad;
        }
    }
    #pragma unroll
    for (int reg = 0; reg < 4; ++reg) {
        #pragma unroll
        for (int off = 8; off > 0; off >>= 1) {     // reduce over 16 cols
            ls[reg] += __shfl_down(ls[reg], off, 16);
            ld[reg] += __shfl_down(ld[reg], off, 16);
        }
    }
    if (r == 0) {
        #pragma unroll
        for (int reg = 0; reg < 4; ++reg) {
            const int n = m0 + q * 4 + reg;
            al_s1[n * HEADS + w] = ls[reg];
            al_d1[n * HEADS + w] = ld[reg];
        }
    }
}

// ---------------------------------------------------------------------------
// Edge-weight precompute, layer 1: w[e][h] = exp(leaky(al_s1[src]+al_d1[dst]))
// stored as 4 bf16 PLANES ew1p[h*EP + e] so each slice pass streams only its
// head's 2 B/edge. al tables are 0.8 MB -> fully L2-cached gathers.
// ---------------------------------------------------------------------------
__global__ void ew1_kernel(const unsigned short* __restrict__ csr_s,
                           const unsigned short* __restrict__ csr_d,
                           const float* __restrict__ al_s1, const float* __restrict__ al_d1,
                           unsigned short* __restrict__ ew1p)
{
    const int i = blockIdx.x * blockDim.x + threadIdx.x;
    if (i >= EP) return;
    const int s = csr_s[i], d = csr_d[i];
    const float4 as = *(const float4*)(al_s1 + s * 4);
    const float4 ad = *(const float4*)(al_d1 + d * 4);
    float t0 = as.x + ad.x; t0 = t0 > 0.f ? t0 : NEG_SLOPE * t0;
    float t1 = as.y + ad.y; t1 = t1 > 0.f ? t1 : NEG_SLOPE * t1;
    float t2 = as.z + ad.z; t2 = t2 > 0.f ? t2 : NEG_SLOPE * t2;
    float t3 = as.w + ad.w; t3 = t3 > 0.f ? t3 : NEG_SLOPE * t3;
    ew1p[0 * EP + i] = f2bf(__expf(t0));
    ew1p[1 * EP + i] = f2bf(__expf(t1));
    ew1p[2 * EP + i] = f2bf(__expf(t2));
    ew1p[3 * EP + i] = f2bf(__expf(t3));
}

// ---------------------------------------------------------------------------
// Layer-1 aggregation, XCD-SLICED. slice = blockIdx%8 -> pinned to one XCD
// under round-robin dispatch; each XCD touches only 64 B of every H1b row
// (3.2 MB working set < 4 MB L2 -> gather becomes L2-resident).
// Block = 4 waves = 4 dsts (one wave per dst-slice). Lane: qt=l>>4 is the
// edge subset (4 edges in flight), j=l&15 covers 2 channels via one uint.
// csr/ew streams use nontemporal loads to not evict the resident slice.
// den identical across the 2 slices of a head (same ew plane) -> consistent.
// ---------------------------------------------------------------------------
__global__ __launch_bounds__(256) void agg1_sliced(
    const int* __restrict__ rowptr, const unsigned short* __restrict__ csr_s,
    const unsigned short* __restrict__ ew1p,
    const unsigned int* __restrict__ H1w, const float* __restrict__ b1,
    unsigned int* __restrict__ out1w)
{
    const int s = blockIdx.x & 7;                       // slice == XCD (assumed)
    const int dst = ((blockIdx.x >> 3) << 2) + (threadIdx.x >> 6);
    const int l = threadIdx.x & 63;
    const int qt = l >> 4, j = l & 15;
    const unsigned short* ewh = ew1p + (size_t)(s >> 1) * EP;   // this slice's head
    const int beg = rowptr[dst], end = rowptr[dst + 1];
    float alo = 0.f, ahi = 0.f, den = 0.f;
    int i = beg + qt;
    for (; i + 4 < end; i += 8) {                       // 2 gathers in flight
        const int src0 = __builtin_nontemporal_load(csr_s + i);
        const int src1 = __builtin_nontemporal_load(csr_s + i + 4);
        const float w0 = bf1(__builtin_nontemporal_load(ewh + i));
        const float w1 = bf1(__builtin_nontemporal_load(ewh + i + 4));
        const unsigned int u0 = H1w[(size_t)src0 * 128 + s * 16 + j];
        const unsigned int u1 = H1w[(size_t)src1 * 128 + s * 16 + j];
        alo += w0 * bf_lo(u0) + w1 * bf_lo(u1);
        ahi += w0 * bf_hi(u0) + w1 * bf_hi(u1);
        den += w0 + w1;
    }
    if (i < end) {
        const int src0 = __builtin_nontemporal_load(csr_s + i);
        const float w0 = bf1(__builtin_nontemporal_load(ewh + i));
        const unsigned int u0 = H1w[(size_t)src0 * 128 + s * 16 + j];
        alo += w0 * bf_lo(u0); ahi += w0 * bf_hi(u0); den += w0;
    }
    #pragma unroll
    for (int m = 16; m <= 32; m <<= 1) {                // combine 4 edge subsets
        alo += __shfl_xor(alo, m, 64);
        ahi += __shfl_xor(ahi, m, 64);
        den += __shfl_xor(den, m, 64);
    }
    if (qt == 0) {
        const float rcp = 1.f / (den + 1e-16f);
        const float2 bb = *(const float2*)(b1 + s * 32 + 2 * j);
        float v0 = alo * rcp + bb.x; v0 = v0 > 0.f ? v0 : 0.f;
        float v1 = ahi * rcp + bb.y; v1 = v1 > 0.f ? v1 : 0.f;
        __builtin_nontemporal_store(pack_bf2(v0, v1),
                                    out1w + (size_t)dst * 128 + s * 16 + j);
    }
}

// ---------------------------------------------------------------------------
// GEMM2 via MFMA + fused layer-2 logits (unchanged).
// ---------------------------------------------------------------------------
__global__ __launch_bounds__(256) void gemm2_mfma(
    const short* __restrict__ out1s, const short* __restrict__ W2p,
    const float* __restrict__ a_src2, const float* __restrict__ a_dst2,
    unsigned short* __restrict__ H2b,
    float* __restrict__ al_s2, float* __restrict__ al_d2)
{
    const int m0 = blockIdx.x * 16;
    const int w = threadIdx.x >> 6;
    const int l = threadIdx.x & 63;
    const int q = l >> 4, r = l & 15;
    floatx4 acc = {};
    const short* arow = out1s + (size_t)(m0 + r) * F1 + q * 8;
    #pragma unroll
    for (int kt = 0; kt < 8; ++kt) {
        const short8 a = *(const short8*)(arow + kt * 32);
        const short8 b = *(const short8*)(W2p + (size_t)((w * 8 + kt) * 64 + l) * 8);
        acc = __builtin_amdgcn_mfma_f32_16x16x32_bf16(a, b, acc, 0, 0, 0);
    }
    const int col = w * 16 + r;
    const float as = a_src2[col], ad = a_dst2[col];
    float ls[4], ld[4];
    #pragma unroll
    for (int reg = 0; reg < 4; ++reg) {
        H2b[(size_t)(m0 + q * 4 + reg) * HID + col] = f2bf(acc[reg]);
        ls[reg] = acc[reg] * as;
        ld[reg] = acc[reg] * ad;
    }
    #pragma unroll
    for (int reg = 0; reg < 4; ++reg) {
        #pragma unroll
        for (int off = 8; off > 0; off >>= 1) {
            ls[reg] += __shfl_down(ls[reg], off, 16);
            ld[reg] += __shfl_down(ld[reg], off, 16);
        }
    }
    __shared__ float Ls[4][16], Ld[4][16];
    if (r == 0) {
        #pragma unroll
        for (int reg = 0; reg < 4; ++reg) {
            Ls[w][q * 4 + reg] = ls[reg];
            Ld[w][q * 4 + reg] = ld[reg];
        }
    }
    __syncthreads();
    if (threadIdx.x < 16) {
        const int row = threadIdx.x;
        al_s2[m0 + row] = Ls[0][row] + Ls[1][row] + Ls[2][row] + Ls[3][row];
        al_d2[m0 + row] = Ld[0][row] + Ld[1][row] + Ld[2][row] + Ld[3][row];
    }
}

// ---------------------------------------------------------------------------
// Edge-weight precompute, layer 2 (H=1): bf16 plane ew2[e].
// ---------------------------------------------------------------------------
__global__ void ew2_kernel(const unsigned short* __restrict__ csr_s,
                           const unsigned short* __restrict__ csr_d,
                           const float* __restrict__ al_s2, const float* __restrict__ al_d2,
                           unsigned short* __restrict__ ew2)
{
    const int i = blockIdx.x * blockDim.x + threadIdx.x;
    if (i >= EP) return;
    const int s = csr_s[i], d = csr_d[i];
    float t = al_s2[s] + al_d2[d];
    t = t > 0.f ? t : NEG_SLOPE * t;
    ew2[i] = f2bf(__expf(t));
}

// ---------------------------------------------------------------------------
// Layer-2 aggregation, XCD-SLICED by 2. slice = blockIdx&1 == (blockIdx%8)&1
// -> even XCDs do slice 0, odd slice 1; per-XCD working set 3.2 MB < 4 MB L2.
// Same wave shape as agg1_sliced (4 edges x 16 lanes x uint).
// ---------------------------------------------------------------------------
__global__ __launch_bounds__(256) void agg2_sliced(
    const int* __restrict__ rowptr, const unsigned short* __restrict__ csr_s,
    const unsigned short* __restrict__ ew2,
    const unsigned int* __restrict__ H2w, float* __restrict__ out2)
{
    const int s = blockIdx.x & 1;
    const int dst = ((blockIdx.x >> 1) << 2) + (threadIdx.x >> 6);
    const int l = threadIdx.x & 63;
    const int qt = l >> 4, j = l & 15;
    const int beg = rowptr[dst], end = rowptr[dst + 1];
    float alo = 0.f, ahi = 0.f, den = 0.f;
    int i = beg + qt;
    for (; i + 4 < end; i += 8) {
        const int src0 = __builtin_nontemporal_load(csr_s + i);
        const int src1 = __builtin_nontemporal_load(csr_s + i + 4);
        const float w0 = bf1(__builtin_nontemporal_load(ew2 + i));
        const float w1 = bf1(__builtin_nontemporal_load(ew2 + i + 4));
        const unsigned int u0 = H2w[(size_t)src0 * 32 + s * 16 + j];
        const unsigned int u1 = H2w[(size_t)src1 * 32 + s * 16 + j];
        alo += w0 * bf_lo(u0) + w1 * bf_lo(u1);
        ahi += w0 * bf_hi(u0) + w1 * bf_hi(u1);
        den += w0 + w1;
    }
    if (i < end) {
        const int src0 = __builtin_nontemporal_load(csr_s + i);
        const float w0 = bf1(__builtin_nontemporal_load(ew2 + i));
        const unsigned int u0 = H2w[(size_t)src0 * 32 + s * 16 + j];
        alo += w0 * bf_lo(u0); ahi += w0 * bf_hi(u0); den += w0;
    }
    #pragma unroll
    for (int m = 16; m <= 32; m <<= 1) {
        alo += __shfl_xor(alo, m, 64);
        ahi += __shfl_xor(ahi, m, 64);
        den += __shfl_xor(den, m, 64);
    }
    if (qt == 0) {
        const float rcp = 1.f / (den + 1e-16f);
        *(float2*)(out2 + (size_t)dst * HID + s * 32 + 2 * j) =
            make_float2(alo * rcp, ahi * rcp);
    }
}

// ---------------------------------------------------------------------------
// Pool (sorted-batch binary search) + FC + log_softmax. b2 folded as count*b2.
// ---------------------------------------------------------------------------
__global__ __launch_bounds__(64) void pool_fc_kernel(
    const float* __restrict__ out2, const float* __restrict__ b2,
    const int* __restrict__ batch,
    const float* __restrict__ fc_w, const float* __restrict__ fc_b,
    float* __restrict__ out)
{
    const int g = blockIdx.x;
    const int c = threadIdx.x;
    __shared__ int se[2];
    if (c < 2) {
        const int target = g + c;  // lower_bound(batch, target)
        int lo = 0, hi = N_NODES;
        while (lo < hi) { int mid = (lo + hi) >> 1; if (batch[mid] < target) lo = mid + 1; else hi = mid; }
        se[c] = lo;
    }
    __syncthreads();
    const int start = se[0], end = se[1];
    float acc = 0.f;
    for (int n = start; n < end; ++n)
        acc += out2[(size_t)n * HID + c];
    acc += (float)(end - start) * b2[c];
    __shared__ float pooled[HID];
    pooled[c] = acc;
    __syncthreads();
    __shared__ float logits[OUT_CH];
    if (c < OUT_CH) {
        float l = fc_b[c];
        #pragma unroll
        for (int k = 0; k < HID; ++k) l += pooled[k] * fc_w[k * OUT_CH + c];
        logits[c] = l;
    }
    __syncthreads();
    if (c == 0) {
        float m = logits[0];
        #pragma unroll
        for (int j2 = 1; j2 < OUT_CH; ++j2) m = fmaxf(m, logits[j2]);
        float s = 0.f;
        #pragma unroll
        for (int j2 = 0; j2 < OUT_CH; ++j2) s += __expf(logits[j2] - m);
        const float lse = m + __logf(s);
        #pragma unroll
        for (int j2 = 0; j2 < OUT_CH; ++j2) out[g * OUT_CH + j2] = logits[j2] - lse;
    }
}

// ---------------------------------------------------------------------------
// Workspace ≈ 85 MB (round-0 layout used ~131 MB and ran fine)
// ---------------------------------------------------------------------------

extern "C" void kernel_launch(void* const* d_in, const int* in_sizes, int n_in,
                              void* d_out, int out_size, void* d_ws, size_t ws_size,
                              hipStream_t stream)
{
    const float* x      = (const float*)d_in[0];
    const int*   ei     = (const int*)  d_in[1];   // [2, 800000] flat: src row, dst row
    const int*   batch  = (const int*)  d_in[2];
    const float* W1     = (const float*)d_in[3];
    const float* a_src1 = (const float*)d_in[4];
    const float* a_dst1 = (const float*)d_in[5];
    const float* b1     = (const float*)d_in[6];
    const float* W2     = (const float*)d_in[7];
    const float* a_src2 = (const float*)d_in[8];
    const float* a_dst2 = (const float*)d_in[9];
    const float* b2     = (const float*)d_in[10];
    const float* fc_w   = (const float*)d_in[11];
    const float* fc_b   = (const float*)d_in[12];
    float* out = (float*)d_out;

    char* ws = (char*)d_ws;
    size_t off = 0;
    auto alloc_b = [&](size_t bytes) { void* p = (void*)(ws + off); off += (bytes + 15) & ~15ull; return p; };

    unsigned short* H1b  = (unsigned short*)alloc_b((size_t)N_NODES * F1 * 2);     // 25.6 MB
    unsigned int*   out1b= (unsigned int*)  alloc_b((size_t)N_NODES * (F1/2) * 4); // 25.6 MB
    float* al_s1  = (float*)alloc_b((size_t)N_NODES * HEADS * 4);
    float* al_d1  = (float*)alloc_b((size_t)N_NODES * HEADS * 4);
    unsigned short* H2b  = (unsigned short*)alloc_b((size_t)N_NODES * HID * 2);    // 6.4 MB
    float* al_s2  = (float*)alloc_b((size_t)N_NODES * 4);
    float* al_d2  = (float*)alloc_b((size_t)N_NODES * 4);
    float* out2   = (float*)alloc_b((size_t)N_NODES * HID * 4);                    // 12.8 MB
    int*   deg    = (int*)alloc_b((size_t)N_NODES * 4);
    int*   rowptr = (int*)alloc_b((size_t)(N_NODES + 1) * 4);
    int*   cursor = (int*)alloc_b((size_t)N_NODES * 4);
    unsigned short* csr_s = (unsigned short*)alloc_b((size_t)EP * 2);              // 1.7 MB
    unsigned short* csr_d = (unsigned short*)alloc_b((size_t)EP * 2);              // 1.7 MB
    unsigned short* ew1p  = (unsigned short*)alloc_b((size_t)HEADS * EP * 2);      // 6.8 MB
    unsigned short* ew2   = (unsigned short*)alloc_b((size_t)EP * 2);              // 1.7 MB
    int*   blocksum = (int*)alloc_b((size_t)SCAN_B * 4);
    unsigned short* W1p = (unsigned short*)alloc_b((size_t)IN_CH * F1 * 2);        // 64 KB
    unsigned short* W2p = (unsigned short*)alloc_b((size_t)F1 * HID * 2);          // 32 KB

    hipMemsetAsync(deg, 0, sizeof(int) * N_NODES, stream);

    // CSR build + W pack
    csr_count_packw<<<(EP + 255) / 256, 256, 0, stream>>>(ei, deg, W1, W1p, W2, W2p);
    csr_scan1  <<<SCAN_B, 256, 0, stream>>>(deg, blocksum);
    csr_scan2  <<<SCAN_B, 256, 0, stream>>>(deg, blocksum, rowptr, cursor);
    csr_scatter<<<(EP + 255) / 256, 256, 0, stream>>>(ei, cursor, csr_s, csr_d);

    // Layer 1
    gemm1_mfma <<<N_NODES / 16, 256, 0, stream>>>(x, (const short*)W1p,
                                                  a_src1, a_dst1, H1b, al_s1, al_d1);
    ew1_kernel <<<(EP + 255) / 256, 256, 0, stream>>>(csr_s, csr_d, al_s1, al_d1, ew1p);
    agg1_sliced<<<8 * (N_NODES / 4), 256, 0, stream>>>(rowptr, csr_s, ew1p,
                                                       (const unsigned int*)H1b, b1,
                                                       (unsigned int*)out1b);

    // Layer 2
    gemm2_mfma <<<N_NODES / 16, 256, 0, stream>>>((const short*)out1b, (const short*)W2p,
                                                  a_src2, a_dst2, H2b, al_s2, al_d2);
    ew2_kernel <<<(EP + 255) / 256, 256, 0, stream>>>(csr_s, csr_d, al_s2, al_d2, ew2);
    agg2_sliced<<<2 * (N_NODES / 4), 256, 0, stream>>>(rowptr, csr_s, ew2,
                                                       (const unsigned int*)H2b, out2);

    // Readout
    pool_fc_kernel<<<NUM_GRAPHS, 64, 0, stream>>>(out2, b2, batch, fc_w, fc_b, out);
}

// Round 12
// 365.118 us; speedup vs baseline: 1.4703x; 1.4703x over previous
//
#include <hip/hip_runtime.h>
#include <hip/hip_bf16.h>
#include <math.h>

// Problem constants (from reference)
#define N_NODES   50000
#define N_EDGES   800000
#define EP        (N_EDGES + N_NODES)   // edges + self loops = 850000
#define IN_CH     128
#define HID       64
#define HEADS     4
#define F1        (HEADS * HID)         // 256
#define OUT_CH    10
#define NUM_GRAPHS 500
#define NEG_SLOPE 0.2f

typedef __attribute__((ext_vector_type(8))) short short8;   // 8 bf16 (4 VGPRs)
typedef __attribute__((ext_vector_type(4))) float floatx4;  // MFMA C/D

// bf16 pack/unpack helpers (RNE)
__device__ __forceinline__ unsigned short f2bf(float f) {
    unsigned int u = __float_as_uint(f);
    u += 0x7FFFu + ((u >> 16) & 1u);
    return (unsigned short)(u >> 16);
}
__device__ __forceinline__ unsigned int pack_bf2(float lo, float hi) {
    return (unsigned int)f2bf(lo) | ((unsigned int)f2bf(hi) << 16);
}
__device__ __forceinline__ float bf_lo(unsigned int u) { return __uint_as_float(u << 16); }
__device__ __forceinline__ float bf_hi(unsigned int u) { return __uint_as_float(u & 0xFFFF0000u); }

// ---------------------------------------------------------------------------
// CSR count (dst histogram) + W pack fused into one dispatch.
// ---------------------------------------------------------------------------
__global__ void csr_count_packw(const int* __restrict__ ei, int* __restrict__ deg,
                                const float* __restrict__ W1, unsigned short* __restrict__ W1p,
                                const float* __restrict__ W2, unsigned short* __restrict__ W2p)
{
    const int gid = blockIdx.x * blockDim.x + threadIdx.x;
    if (gid < EP) {
        const int dst = (gid < N_EDGES) ? ei[N_EDGES + gid] : gid - N_EDGES;
        atomicAdd(&deg[dst], 1);
    }
    if (gid < 4096) {                                        // W1: 16 nt x 4 kt x 64
        const int t = gid >> 8, kt = (gid >> 6) & 3, l = gid & 63;
        const int col = t * 16 + (l & 15);
        unsigned short* o = W1p + (size_t)((t * 4 + kt) * 64 + l) * 8;
        #pragma unroll
        for (int j = 0; j < 8; ++j) {
            const int k = kt * 32 + (l >> 4) * 8 + j;
            o[j] = f2bf(W1[k * F1 + col]);
        }
    } else if (gid < 6144) {                                 // W2: 4 nt x 8 kt x 64
        const int g2 = gid - 4096;
        const int t = g2 >> 9, kt = (g2 >> 6) & 7, l = g2 & 63;
        const int col = t * 16 + (l & 15);
        unsigned short* o = W2p + (size_t)((t * 8 + kt) * 64 + l) * 8;
        #pragma unroll
        for (int j = 0; j < 8; ++j) {
            const int k = kt * 32 + (l >> 4) * 8 + j;
            o[j] = f2bf(W2[k * HID + col]);
        }
    }
}

#define SCAN_B 196                       // ceil(50000 / 256)
__global__ __launch_bounds__(256) void csr_scan1(
    const int* __restrict__ deg, int* __restrict__ blocksum)
{
    const int b = blockIdx.x, t = threadIdx.x;
    const int i = b * 256 + t;
    __shared__ int sm[256];
    sm[t] = (i < N_NODES) ? deg[i] : 0;
    __syncthreads();
    for (int off = 128; off > 0; off >>= 1) {
        if (t < off) sm[t] += sm[t + off];
        __syncthreads();
    }
    if (t == 0) blocksum[b] = sm[0];
}
__global__ __launch_bounds__(256) void csr_scan2(
    const int* __restrict__ deg, const int* __restrict__ blocksum,
    int* __restrict__ rowptr, int* __restrict__ cursor)
{
    const int b = blockIdx.x, t = threadIdx.x;
    __shared__ int sm[256];
    sm[t] = (t < b) ? blocksum[t] : 0;     // b < SCAN_B <= 256
    __syncthreads();
    for (int off = 128; off > 0; off >>= 1) {
        if (t < off) sm[t] += sm[t + off];
        __syncthreads();
    }
    const int base = sm[0];
    __syncthreads();
    const int i = b * 256 + t;
    const int d = (i < N_NODES) ? deg[i] : 0;
    sm[t] = d;
    __syncthreads();
    for (int off = 1; off < 256; off <<= 1) {   // inclusive scan
        int u = (t >= off) ? sm[t - off] : 0;
        __syncthreads();
        if (t >= off) sm[t] += u;
        __syncthreads();
    }
    const int excl = base + sm[t] - d;
    if (i < N_NODES) { rowptr[i] = excl; cursor[i] = excl; }
    if (i == N_NODES - 1) rowptr[N_NODES] = excl + d;   // == EP
}

__global__ void csr_scatter(const int* __restrict__ ei,
                            int* __restrict__ cursor, int* __restrict__ csr_src)
{
    const int e = blockIdx.x * blockDim.x + threadIdx.x;
    if (e >= EP) return;
    int src, dst;
    if (e < N_EDGES) { src = ei[e]; dst = ei[N_EDGES + e]; }
    else             { src = dst = e - N_EDGES; }
    const int pos = atomicAdd(&cursor[dst], 1);
    csr_src[pos] = src;
}

// ---------------------------------------------------------------------------
// GEMM1 via MFMA + fused layer-1 logits (unchanged from round 9/10).
// ---------------------------------------------------------------------------
__global__ __launch_bounds__(256) void gemm1_mfma(
    const float* __restrict__ x, const short* __restrict__ W1p,
    const float* __restrict__ a_src1, const float* __restrict__ a_dst1,
    unsigned short* __restrict__ H1b,
    float* __restrict__ al_s1, float* __restrict__ al_d1)
{
    const int m0 = blockIdx.x * 16;
    const int w = threadIdx.x >> 6;
    const int l = threadIdx.x & 63;
    const int q = l >> 4, r = l & 15;
    floatx4 acc[4] = {};
    const float* arow = x + (size_t)(m0 + r) * IN_CH + q * 8;
    #pragma unroll
    for (int kt = 0; kt < 4; ++kt) {
        const float4 f0 = *(const float4*)(arow + kt * 32);
        const float4 f1 = *(const float4*)(arow + kt * 32 + 4);
        union { uint4 u; short8 s; } a;
        a.u = make_uint4(pack_bf2(f0.x, f0.y), pack_bf2(f0.z, f0.w),
                         pack_bf2(f1.x, f1.y), pack_bf2(f1.z, f1.w));
        #pragma unroll
        for (int t = 0; t < 4; ++t) {
            const int nt = w * 4 + t;
            const short8 b = *(const short8*)(W1p + (size_t)((nt * 4 + kt) * 64 + l) * 8);
            acc[t] = __builtin_amdgcn_mfma_f32_16x16x32_bf16(a.s, b, acc[t], 0, 0, 0);
        }
    }
    float ls[4] = {0.f, 0.f, 0.f, 0.f}, ld[4] = {0.f, 0.f, 0.f, 0.f};
    #pragma unroll
    for (int t = 0; t < 4; ++t) {
        const int col = (w * 4 + t) * 16 + r;
        const float as = a_src1[col], ad = a_dst1[col];
        #pragma unroll
        for (int reg = 0; reg < 4; ++reg) {
            H1b[(size_t)(m0 + q * 4 + reg) * F1 + col] = f2bf(acc[t][reg]);
            ls[reg] += acc[t][reg] * as;
            ld[reg] += acc[t][reg] * ad;
        }
    }
    #pragma unroll
    for (int reg = 0; reg < 4; ++reg) {
        #pragma unroll
        for (int off = 8; off > 0; off >>= 1) {     // reduce over 16 cols
            ls[reg] += __shfl_down(ls[reg], off, 16);
            ld[reg] += __shfl_down(ld[reg], off, 16);
        }
    }
    if (r == 0) {
        #pragma unroll
        for (int reg = 0; reg < 4; ++reg) {
            const int n = m0 + q * 4 + reg;
            al_s1[n * HEADS + w] = ls[reg];
            al_d1[n * HEADS + w] = ld[reg];
        }
    }
}

// ---------------------------------------------------------------------------
// FUSED layer-1 aggregation + GEMM2 + layer-2 logits. Block = 16 dsts.
// Phase A (round-10 agg1): wave w aggregates dsts m0+4w..+3; lane l owns
// channels 4l..4l+3 (head l>>4); register staging + shfl broadcast of
// per-edge weights, 4 gathers in flight. Result rows (bias+relu, bf16)
// go to LDS instead of global -> out1b round-trip (51 MB) eliminated.
// Phase B (round-10 gemm2): MFMA from LDS rows x W2p -> H2b + al_s2/al_d2.
// ---------------------------------------------------------------------------
__global__ __launch_bounds__(256) void agg1_gemm2(
    const int* __restrict__ rowptr, const int* __restrict__ csr_src,
    const float* __restrict__ al_s1, const float* __restrict__ al_d1,
    const uint2* __restrict__ H1b2, const float* __restrict__ b1,
    const short* __restrict__ W2p,
    const float* __restrict__ a_src2, const float* __restrict__ a_dst2,
    unsigned short* __restrict__ H2b,
    float* __restrict__ al_s2, float* __restrict__ al_d2)
{
    const int m0 = blockIdx.x * 16;
    const int w = threadIdx.x >> 6;
    const int l = threadIdx.x & 63;
    __shared__ unsigned int rows[16][128];      // out1 rows: uint u = ch {2u,2u+1}

    // ---- phase A ----
    const int h = l >> 4;                       // this lane's head
    for (int d = 0; d < 4; ++d) {
        const int dst = m0 + w * 4 + d;
        const int beg = rowptr[dst], end = rowptr[dst + 1];
        const float4 ad = *(const float4*)(al_d1 + dst * 4);
        float a0 = 0.f, a1 = 0.f, a2 = 0.f, a3 = 0.f, den = 0.f;
        for (int base = beg; base < end; base += 64) {
            const int n = min(64, end - base);
            int s_reg = 0;
            float w0 = 0.f, w1 = 0.f, w2 = 0.f, w3 = 0.f;
            if (l < n) {
                s_reg = csr_src[base + l];
                const float4 as = *(const float4*)(al_s1 + s_reg * 4);
                float t0 = as.x + ad.x; t0 = t0 > 0.f ? t0 : NEG_SLOPE * t0;
                float t1 = as.y + ad.y; t1 = t1 > 0.f ? t1 : NEG_SLOPE * t1;
                float t2 = as.z + ad.z; t2 = t2 > 0.f ? t2 : NEG_SLOPE * t2;
                float t3 = as.w + ad.w; t3 = t3 > 0.f ? t3 : NEG_SLOPE * t3;
                w0 = __expf(t0); w1 = __expf(t1); w2 = __expf(t2); w3 = __expf(t3);
            }
            const int n4 = (n + 3) & ~3;        // padded lanes carry w=0, s=0
            for (int i = 0; i < n4; i += 4) {
                int   srcj[4];
                float wtj[4];
                #pragma unroll
                for (int j = 0; j < 4; ++j) {
                    const int idx = i + j;
                    srcj[j] = __shfl(s_reg, idx, 64);
                    const float t0 = __shfl(w0, idx, 64);
                    const float t1 = __shfl(w1, idx, 64);
                    const float t2 = __shfl(w2, idx, 64);
                    const float t3 = __shfl(w3, idx, 64);
                    wtj[j] = h == 0 ? t0 : (h == 1 ? t1 : (h == 2 ? t2 : t3));
                }
                uint2 u[4];
                #pragma unroll
                for (int j = 0; j < 4; ++j)
                    u[j] = H1b2[(size_t)srcj[j] * (F1 / 4) + l];   // 4 in flight
                #pragma unroll
                for (int j = 0; j < 4; ++j) {
                    a0 += wtj[j] * bf_lo(u[j].x); a1 += wtj[j] * bf_hi(u[j].x);
                    a2 += wtj[j] * bf_lo(u[j].y); a3 += wtj[j] * bf_hi(u[j].y);
                    den += wtj[j];
                }
            }
        }
        const float rcp = 1.f / (den + 1e-16f);
        const float4 bb = *(const float4*)(b1 + 4 * l);
        float v0 = a0 * rcp + bb.x; v0 = v0 > 0.f ? v0 : 0.f;
        float v1 = a1 * rcp + bb.y; v1 = v1 > 0.f ? v1 : 0.f;
        float v2 = a2 * rcp + bb.z; v2 = v2 > 0.f ? v2 : 0.f;
        float v3 = a3 * rcp + bb.w; v3 = v3 > 0.f ? v3 : 0.f;
        rows[w * 4 + d][2 * l]     = pack_bf2(v0, v1);
        rows[w * 4 + d][2 * l + 1] = pack_bf2(v2, v3);
    }
    __syncthreads();

    // ---- phase B: H2 = rows @ W2 (wave w owns n-tile w) ----
    const int q = l >> 4, r = l & 15;
    floatx4 acc = {};
    #pragma unroll
    for (int kt = 0; kt < 8; ++kt) {
        union { uint4 u; short8 s; } a;
        a.u = *(const uint4*)&rows[r][kt * 16 + q * 4];   // ds_read_b128
        const short8 b = *(const short8*)(W2p + (size_t)((w * 8 + kt) * 64 + l) * 8);
        acc = __builtin_amdgcn_mfma_f32_16x16x32_bf16(a.s, b, acc, 0, 0, 0);
    }
    const int col = w * 16 + r;
    const float as = a_src2[col], ad2 = a_dst2[col];
    float ls[4], ld[4];
    #pragma unroll
    for (int reg = 0; reg < 4; ++reg) {
        H2b[(size_t)(m0 + q * 4 + reg) * HID + col] = f2bf(acc[reg]);
        ls[reg] = acc[reg] * as;
        ld[reg] = acc[reg] * ad2;
    }
    #pragma unroll
    for (int reg = 0; reg < 4; ++reg) {
        #pragma unroll
        for (int off = 8; off > 0; off >>= 1) {
            ls[reg] += __shfl_down(ls[reg], off, 16);
            ld[reg] += __shfl_down(ld[reg], off, 16);
        }
    }
    __shared__ float Ls[4][16], Ld[4][16];
    if (r == 0) {
        #pragma unroll
        for (int reg = 0; reg < 4; ++reg) {
            Ls[w][q * 4 + reg] = ls[reg];
            Ld[w][q * 4 + reg] = ld[reg];
        }
    }
    __syncthreads();
    if (threadIdx.x < 16) {
        const int row = threadIdx.x;
        al_s2[m0 + row] = Ls[0][row] + Ls[1][row] + Ls[2][row] + Ls[3][row];
        al_d2[m0 + row] = Ld[0][row] + Ld[1][row] + Ld[2][row] + Ld[3][row];
    }
}

// ---------------------------------------------------------------------------
// FUSED layer-2 aggregation + global_add_pool. Round-10 agg2 body (4 dsts/
// block, quarter-wave x2 unroll, 8 edges in flight), but the epilogue
// atomicAdds into pooled[batch[dst]*64+c] -> out2 buffer (25.6 MB of
// write+read) and the serial pool loop eliminated. pooled is 128 KB; each
// address receives ~100 adds spread over independent chains -> low contention.
// ---------------------------------------------------------------------------
__global__ __launch_bounds__(256) void agg2_pool(
    const int* __restrict__ rowptr, const int* __restrict__ csr_src,
    const float* __restrict__ al_s2, const float* __restrict__ al_d2,
    const uint2* __restrict__ H2b2, const int* __restrict__ batch,
    float* __restrict__ pooled)
{
    const int dst = blockIdx.x * 4 + (threadIdx.x >> 6);
    const int l = threadIdx.x & 63;
    const int qt = l >> 4, j = l & 15;
    const int beg = rowptr[dst], end = rowptr[dst + 1];
    const float ad = al_d2[dst];
    float a0 = 0.f, a1 = 0.f, a2 = 0.f, a3 = 0.f, den = 0.f;
    for (int base = beg; base < end; base += 64) {
        const int n = min(64, end - base);
        int s_reg = 0;
        float w_reg = 0.f;
        if (l < n) {
            s_reg = csr_src[base + l];
            float t = al_s2[s_reg] + ad;
            t = t > 0.f ? t : NEG_SLOPE * t;
            w_reg = __expf(t);
        }
        const int n8 = (n + 7) & ~7;            // padded: w=0, s=0
        for (int i = 0; i < n8; i += 8) {
            const int e0 = i + qt, e1 = i + 4 + qt;
            const int   src0 = __shfl(s_reg, e0, 64), src1 = __shfl(s_reg, e1, 64);
            const float wt0  = __shfl(w_reg, e0, 64), wt1  = __shfl(w_reg, e1, 64);
            const uint2 u0 = H2b2[(size_t)src0 * (HID / 4) + j];
            const uint2 u1 = H2b2[(size_t)src1 * (HID / 4) + j];
            a0 += wt0 * bf_lo(u0.x) + wt1 * bf_lo(u1.x);
            a1 += wt0 * bf_hi(u0.x) + wt1 * bf_hi(u1.x);
            a2 += wt0 * bf_lo(u0.y) + wt1 * bf_lo(u1.y);
            a3 += wt0 * bf_hi(u0.y) + wt1 * bf_hi(u1.y);
            den += wt0 + wt1;
        }
    }
    #pragma unroll
    for (int m = 16; m <= 32; m <<= 1) {        // combine 4 edge subsets
        a0 += __shfl_xor(a0, m, 64);
        a1 += __shfl_xor(a1, m, 64);
        a2 += __shfl_xor(a2, m, 64);
        a3 += __shfl_xor(a3, m, 64);
        den += __shfl_xor(den, m, 64);
    }
    if (l < 16) {
        const float rcp = 1.f / (den + 1e-16f);
        float* p = pooled + (size_t)batch[dst] * HID + 4 * j;
        atomicAdd(p + 0, a0 * rcp);
        atomicAdd(p + 1, a1 * rcp);
        atomicAdd(p + 2, a2 * rcp);
        atomicAdd(p + 3, a3 * rcp);
    }
}

// ---------------------------------------------------------------------------
// Final FC + log_softmax on pooled sums. b2 folded as count*b2 (count via
// binary search on the sorted batch array).
// ---------------------------------------------------------------------------
__global__ __launch_bounds__(64) void fc_final(
    const float* __restrict__ pooled, const float* __restrict__ b2,
    const int* __restrict__ batch,
    const float* __restrict__ fc_w, const float* __restrict__ fc_b,
    float* __restrict__ out)
{
    const int g = blockIdx.x;
    const int c = threadIdx.x;
    __shared__ int se[2];
    if (c < 2) {
        const int target = g + c;  // lower_bound(batch, target)
        int lo = 0, hi = N_NODES;
        while (lo < hi) { int mid = (lo + hi) >> 1; if (batch[mid] < target) lo = mid + 1; else hi = mid; }
        se[c] = lo;
    }
    __syncthreads();
    const int cnt = se[1] - se[0];
    __shared__ float pl[HID];
    pl[c] = pooled[g * HID + c] + (float)cnt * b2[c];
    __syncthreads();
    __shared__ float logits[OUT_CH];
    if (c < OUT_CH) {
        float l = fc_b[c];
        #pragma unroll
        for (int k = 0; k < HID; ++k) l += pl[k] * fc_w[k * OUT_CH + c];
        logits[c] = l;
    }
    __syncthreads();
    if (c == 0) {
        float m = logits[0];
        #pragma unroll
        for (int j2 = 1; j2 < OUT_CH; ++j2) m = fmaxf(m, logits[j2]);
        float s = 0.f;
        #pragma unroll
        for (int j2 = 0; j2 < OUT_CH; ++j2) s += __expf(logits[j2] - m);
        const float lse = m + __logf(s);
        #pragma unroll
        for (int j2 = 0; j2 < OUT_CH; ++j2) out[g * OUT_CH + j2] = logits[j2] - lse;
    }
}

// ---------------------------------------------------------------------------
// Workspace ≈ 40 MB (out1b/out2 eliminated)
// ---------------------------------------------------------------------------

extern "C" void kernel_launch(void* const* d_in, const int* in_sizes, int n_in,
                              void* d_out, int out_size, void* d_ws, size_t ws_size,
                              hipStream_t stream)
{
    const float* x      = (const float*)d_in[0];
    const int*   ei     = (const int*)  d_in[1];   // [2, 800000] flat: src row, dst row
    const int*   batch  = (const int*)  d_in[2];
    const float* W1     = (const float*)d_in[3];
    const float* a_src1 = (const float*)d_in[4];
    const float* a_dst1 = (const float*)d_in[5];
    const float* b1     = (const float*)d_in[6];
    const float* W2     = (const float*)d_in[7];
    const float* a_src2 = (const float*)d_in[8];
    const float* a_dst2 = (const float*)d_in[9];
    const float* b2     = (const float*)d_in[10];
    const float* fc_w   = (const float*)d_in[11];
    const float* fc_b   = (const float*)d_in[12];
    float* out = (float*)d_out;

    char* ws = (char*)d_ws;
    size_t off = 0;
    auto alloc_b = [&](size_t bytes) { void* p = (void*)(ws + off); off += (bytes + 15) & ~15ull; return p; };

    unsigned short* H1b  = (unsigned short*)alloc_b((size_t)N_NODES * F1 * 2);     // 25.6 MB
    float* al_s1  = (float*)alloc_b((size_t)N_NODES * HEADS * 4);
    float* al_d1  = (float*)alloc_b((size_t)N_NODES * HEADS * 4);
    unsigned short* H2b  = (unsigned short*)alloc_b((size_t)N_NODES * HID * 2);    // 6.4 MB
    float* al_s2  = (float*)alloc_b((size_t)N_NODES * 4);
    float* al_d2  = (float*)alloc_b((size_t)N_NODES * 4);
    float* pooled = (float*)alloc_b((size_t)NUM_GRAPHS * HID * 4);                 // 128 KB
    int*   deg    = (int*)alloc_b((size_t)N_NODES * 4);
    int*   rowptr = (int*)alloc_b((size_t)(N_NODES + 1) * 4);
    int*   cursor = (int*)alloc_b((size_t)N_NODES * 4);
    int*   csr_src= (int*)alloc_b((size_t)EP * 4);                                 // 3.4 MB
    int*   blocksum = (int*)alloc_b((size_t)SCAN_B * 4);
    unsigned short* W1p = (unsigned short*)alloc_b((size_t)IN_CH * F1 * 2);        // 64 KB
    unsigned short* W2p = (unsigned short*)alloc_b((size_t)F1 * HID * 2);          // 32 KB

    hipMemsetAsync(deg, 0, sizeof(int) * N_NODES, stream);
    hipMemsetAsync(pooled, 0, sizeof(float) * NUM_GRAPHS * HID, stream);

    // CSR build + W pack
    csr_count_packw<<<(EP + 255) / 256, 256, 0, stream>>>(ei, deg, W1, W1p, W2, W2p);
    csr_scan1  <<<SCAN_B, 256, 0, stream>>>(deg, blocksum);
    csr_scan2  <<<SCAN_B, 256, 0, stream>>>(deg, blocksum, rowptr, cursor);
    csr_scatter<<<(EP + 255) / 256, 256, 0, stream>>>(ei, cursor, csr_src);

    // Layer 1 GEMM (+ layer-1 logits)
    gemm1_mfma<<<N_NODES / 16, 256, 0, stream>>>(x, (const short*)W1p,
                                                 a_src1, a_dst1, H1b, al_s1, al_d1);

    // Fused: layer-1 aggregation -> (LDS) -> GEMM2 (+ layer-2 logits)
    agg1_gemm2<<<N_NODES / 16, 256, 0, stream>>>(rowptr, csr_src, al_s1, al_d1,
                                                 (const uint2*)H1b, b1,
                                                 (const short*)W2p, a_src2, a_dst2,
                                                 H2b, al_s2, al_d2);

    // Fused: layer-2 aggregation -> atomic global_add_pool
    agg2_pool<<<N_NODES / 4, 256, 0, stream>>>(rowptr, csr_src, al_s2, al_d2,
                                               (const uint2*)H2b, batch, pooled);

    // Readout
    fc_final<<<NUM_GRAPHS, 64, 0, stream>>>(pooled, b2, batch, fc_w, fc_b, out);
}

// Round 13
// 344.593 us; speedup vs baseline: 1.5579x; 1.0596x over previous
//
#include <hip/hip_runtime.h>
#include <hip/hip_bf16.h>
#include <math.h>

// Problem constants (from reference)
#define N_NODES   50000
#define N_EDGES   800000
#define EP        (N_EDGES + N_NODES)   // edges + self loops = 850000
#define IN_CH     128
#define HID       64
#define HEADS     4
#define F1        (HEADS * HID)         // 256
#define OUT_CH    10
#define NUM_GRAPHS 500
#define NEG_SLOPE 0.2f

typedef __attribute__((ext_vector_type(8))) short short8;   // 8 bf16 (4 VGPRs)
typedef __attribute__((ext_vector_type(4))) float floatx4;  // MFMA C/D

// bf16 pack/unpack helpers (RNE)
__device__ __forceinline__ unsigned short f2bf(float f) {
    unsigned int u = __float_as_uint(f);
    u += 0x7FFFu + ((u >> 16) & 1u);
    return (unsigned short)(u >> 16);
}
__device__ __forceinline__ unsigned int pack_bf2(float lo, float hi) {
    return (unsigned int)f2bf(lo) | ((unsigned int)f2bf(hi) << 16);
}
__device__ __forceinline__ float bf_lo(unsigned int u) { return __uint_as_float(u << 16); }
__device__ __forceinline__ float bf_hi(unsigned int u) { return __uint_as_float(u & 0xFFFF0000u); }

// ---------------------------------------------------------------------------
// CSR count (dst histogram) + W pack fused into one dispatch.
// ---------------------------------------------------------------------------
__global__ void csr_count_packw(const int* __restrict__ ei, int* __restrict__ deg,
                                const float* __restrict__ W1, unsigned short* __restrict__ W1p,
                                const float* __restrict__ W2, unsigned short* __restrict__ W2p)
{
    const int gid = blockIdx.x * blockDim.x + threadIdx.x;
    if (gid < EP) {
        const int dst = (gid < N_EDGES) ? ei[N_EDGES + gid] : gid - N_EDGES;
        atomicAdd(&deg[dst], 1);
    }
    if (gid < 4096) {                                        // W1: 16 nt x 4 kt x 64
        const int t = gid >> 8, kt = (gid >> 6) & 3, l = gid & 63;
        const int col = t * 16 + (l & 15);
        unsigned short* o = W1p + (size_t)((t * 4 + kt) * 64 + l) * 8;
        #pragma unroll
        for (int j = 0; j < 8; ++j) {
            const int k = kt * 32 + (l >> 4) * 8 + j;
            o[j] = f2bf(W1[k * F1 + col]);
        }
    } else if (gid < 6144) {                                 // W2: 4 nt x 8 kt x 64
        const int g2 = gid - 4096;
        const int t = g2 >> 9, kt = (g2 >> 6) & 7, l = g2 & 63;
        const int col = t * 16 + (l & 15);
        unsigned short* o = W2p + (size_t)((t * 8 + kt) * 64 + l) * 8;
        #pragma unroll
        for (int j = 0; j < 8; ++j) {
            const int k = kt * 32 + (l >> 4) * 8 + j;
            o[j] = f2bf(W2[k * HID + col]);
        }
    }
}

#define SCAN_B 196                       // ceil(50000 / 256)
__global__ __launch_bounds__(256) void csr_scan1(
    const int* __restrict__ deg, int* __restrict__ blocksum)
{
    const int b = blockIdx.x, t = threadIdx.x;
    const int i = b * 256 + t;
    __shared__ int sm[256];
    sm[t] = (i < N_NODES) ? deg[i] : 0;
    __syncthreads();
    for (int off = 128; off > 0; off >>= 1) {
        if (t < off) sm[t] += sm[t + off];
        __syncthreads();
    }
    if (t == 0) blocksum[b] = sm[0];
}
__global__ __launch_bounds__(256) void csr_scan2(
    const int* __restrict__ deg, const int* __restrict__ blocksum,
    int* __restrict__ rowptr, int* __restrict__ cursor)
{
    const int b = blockIdx.x, t = threadIdx.x;
    __shared__ int sm[256];
    sm[t] = (t < b) ? blocksum[t] : 0;     // b < SCAN_B <= 256
    __syncthreads();
    for (int off = 128; off > 0; off >>= 1) {
        if (t < off) sm[t] += sm[t + off];
        __syncthreads();
    }
    const int base = sm[0];
    __syncthreads();
    const int i = b * 256 + t;
    const int d = (i < N_NODES) ? deg[i] : 0;
    sm[t] = d;
    __syncthreads();
    for (int off = 1; off < 256; off <<= 1) {   // inclusive scan
        int u = (t >= off) ? sm[t - off] : 0;
        __syncthreads();
        if (t >= off) sm[t] += u;
        __syncthreads();
    }
    const int excl = base + sm[t] - d;
    if (i < N_NODES) { rowptr[i] = excl; cursor[i] = excl; }
    if (i == N_NODES - 1) rowptr[N_NODES] = excl + d;   // == EP
}

__global__ void csr_scatter(const int* __restrict__ ei,
                            int* __restrict__ cursor, int* __restrict__ csr_src)
{
    const int e = blockIdx.x * blockDim.x + threadIdx.x;
    if (e >= EP) return;
    int src, dst;
    if (e < N_EDGES) { src = ei[e]; dst = ei[N_EDGES + e]; }
    else             { src = dst = e - N_EDGES; }
    const int pos = atomicAdd(&cursor[dst], 1);
    csr_src[pos] = src;
}

// ---------------------------------------------------------------------------
// GEMM1 via MFMA + fused layer-1 logits (unchanged from round 9/10).
// ---------------------------------------------------------------------------
__global__ __launch_bounds__(256) void gemm1_mfma(
    const float* __restrict__ x, const short* __restrict__ W1p,
    const float* __restrict__ a_src1, const float* __restrict__ a_dst1,
    unsigned short* __restrict__ H1b,
    float* __restrict__ al_s1, float* __restrict__ al_d1)
{
    const int m0 = blockIdx.x * 16;
    const int w = threadIdx.x >> 6;
    const int l = threadIdx.x & 63;
    const int q = l >> 4, r = l & 15;
    floatx4 acc[4] = {};
    const float* arow = x + (size_t)(m0 + r) * IN_CH + q * 8;
    #pragma unroll
    for (int kt = 0; kt < 4; ++kt) {
        const float4 f0 = *(const float4*)(arow + kt * 32);
        const float4 f1 = *(const float4*)(arow + kt * 32 + 4);
        union { uint4 u; short8 s; } a;
        a.u = make_uint4(pack_bf2(f0.x, f0.y), pack_bf2(f0.z, f0.w),
                         pack_bf2(f1.x, f1.y), pack_bf2(f1.z, f1.w));
        #pragma unroll
        for (int t = 0; t < 4; ++t) {
            const int nt = w * 4 + t;
            const short8 b = *(const short8*)(W1p + (size_t)((nt * 4 + kt) * 64 + l) * 8);
            acc[t] = __builtin_amdgcn_mfma_f32_16x16x32_bf16(a.s, b, acc[t], 0, 0, 0);
        }
    }
    float ls[4] = {0.f, 0.f, 0.f, 0.f}, ld[4] = {0.f, 0.f, 0.f, 0.f};
    #pragma unroll
    for (int t = 0; t < 4; ++t) {
        const int col = (w * 4 + t) * 16 + r;
        const float as = a_src1[col], ad = a_dst1[col];
        #pragma unroll
        for (int reg = 0; reg < 4; ++reg) {
            H1b[(size_t)(m0 + q * 4 + reg) * F1 + col] = f2bf(acc[t][reg]);
            ls[reg] += acc[t][reg] * as;
            ld[reg] += acc[t][reg] * ad;
        }
    }
    #pragma unroll
    for (int reg = 0; reg < 4; ++reg) {
        #pragma unroll
        for (int off = 8; off > 0; off >>= 1) {     // reduce over 16 cols
            ls[reg] += __shfl_down(ls[reg], off, 16);
            ld[reg] += __shfl_down(ld[reg], off, 16);
        }
    }
    if (r == 0) {
        #pragma unroll
        for (int reg = 0; reg < 4; ++reg) {
            const int n = m0 + q * 4 + reg;
            al_s1[n * HEADS + w] = ls[reg];
            al_d1[n * HEADS + w] = ld[reg];
        }
    }
}

// ---------------------------------------------------------------------------
// FUSED layer-1 aggregation + GEMM2 + layer-2 logits. Block = 16 dsts.
// Phase A (round-10 agg1): wave w aggregates dsts m0+4w..+3; results to LDS.
// Phase B: MFMA from LDS rows x W2p -> H2b + al_s2/al_d2.
// LDS rows padded to 132 uints/row (stride%32==4): phase-B b128 reads by
// 16 same-q lanes spread over 8 bank groups (2-way aliasing = free, m136)
// instead of all hitting one bank (16-way, the 2.8M conflicts in round 12).
// 132*4=528 B keeps every uint4 read 16B-aligned.
// ---------------------------------------------------------------------------
#define RPAD 132
__global__ __launch_bounds__(256) void agg1_gemm2(
    const int* __restrict__ rowptr, const int* __restrict__ csr_src,
    const float* __restrict__ al_s1, const float* __restrict__ al_d1,
    const uint2* __restrict__ H1b2, const float* __restrict__ b1,
    const short* __restrict__ W2p,
    const float* __restrict__ a_src2, const float* __restrict__ a_dst2,
    unsigned short* __restrict__ H2b,
    float* __restrict__ al_s2, float* __restrict__ al_d2)
{
    const int m0 = blockIdx.x * 16;
    const int w = threadIdx.x >> 6;
    const int l = threadIdx.x & 63;
    __shared__ unsigned int rows[16][RPAD];     // out1 rows: uint u = ch {2u,2u+1}

    // ---- phase A ----
    const int h = l >> 4;                       // this lane's head
    for (int d = 0; d < 4; ++d) {
        const int dst = m0 + w * 4 + d;
        const int beg = rowptr[dst], end = rowptr[dst + 1];
        const float4 ad = *(const float4*)(al_d1 + dst * 4);
        float a0 = 0.f, a1 = 0.f, a2 = 0.f, a3 = 0.f, den = 0.f;
        for (int base = beg; base < end; base += 64) {
            const int n = min(64, end - base);
            int s_reg = 0;
            float w0 = 0.f, w1 = 0.f, w2 = 0.f, w3 = 0.f;
            if (l < n) {
                s_reg = csr_src[base + l];
                const float4 as = *(const float4*)(al_s1 + s_reg * 4);
                float t0 = as.x + ad.x; t0 = t0 > 0.f ? t0 : NEG_SLOPE * t0;
                float t1 = as.y + ad.y; t1 = t1 > 0.f ? t1 : NEG_SLOPE * t1;
                float t2 = as.z + ad.z; t2 = t2 > 0.f ? t2 : NEG_SLOPE * t2;
                float t3 = as.w + ad.w; t3 = t3 > 0.f ? t3 : NEG_SLOPE * t3;
                w0 = __expf(t0); w1 = __expf(t1); w2 = __expf(t2); w3 = __expf(t3);
            }
            const int n4 = (n + 3) & ~3;        // padded lanes carry w=0, s=0
            for (int i = 0; i < n4; i += 4) {
                int   srcj[4];
                float wtj[4];
                #pragma unroll
                for (int j = 0; j < 4; ++j) {
                    const int idx = i + j;
                    srcj[j] = __shfl(s_reg, idx, 64);
                    const float t0 = __shfl(w0, idx, 64);
                    const float t1 = __shfl(w1, idx, 64);
                    const float t2 = __shfl(w2, idx, 64);
                    const float t3 = __shfl(w3, idx, 64);
                    wtj[j] = h == 0 ? t0 : (h == 1 ? t1 : (h == 2 ? t2 : t3));
                }
                uint2 u[4];
                #pragma unroll
                for (int j = 0; j < 4; ++j)
                    u[j] = H1b2[(size_t)srcj[j] * (F1 / 4) + l];   // 4 in flight
                #pragma unroll
                for (int j = 0; j < 4; ++j) {
                    a0 += wtj[j] * bf_lo(u[j].x); a1 += wtj[j] * bf_hi(u[j].x);
                    a2 += wtj[j] * bf_lo(u[j].y); a3 += wtj[j] * bf_hi(u[j].y);
                    den += wtj[j];
                }
            }
        }
        const float rcp = 1.f / (den + 1e-16f);
        const float4 bb = *(const float4*)(b1 + 4 * l);
        float v0 = a0 * rcp + bb.x; v0 = v0 > 0.f ? v0 : 0.f;
        float v1 = a1 * rcp + bb.y; v1 = v1 > 0.f ? v1 : 0.f;
        float v2 = a2 * rcp + bb.z; v2 = v2 > 0.f ? v2 : 0.f;
        float v3 = a3 * rcp + bb.w; v3 = v3 > 0.f ? v3 : 0.f;
        rows[w * 4 + d][2 * l]     = pack_bf2(v0, v1);
        rows[w * 4 + d][2 * l + 1] = pack_bf2(v2, v3);
    }
    __syncthreads();

    // ---- phase B: H2 = rows @ W2 (wave w owns n-tile w) ----
    const int q = l >> 4, r = l & 15;
    floatx4 acc = {};
    #pragma unroll
    for (int kt = 0; kt < 8; ++kt) {
        union { uint4 u; short8 s; } a;
        a.u = *(const uint4*)&rows[r][kt * 16 + q * 4];   // ds_read_b128
        const short8 b = *(const short8*)(W2p + (size_t)((w * 8 + kt) * 64 + l) * 8);
        acc = __builtin_amdgcn_mfma_f32_16x16x32_bf16(a.s, b, acc, 0, 0, 0);
    }
    const int col = w * 16 + r;
    const float as = a_src2[col], ad2 = a_dst2[col];
    float ls[4], ld[4];
    #pragma unroll
    for (int reg = 0; reg < 4; ++reg) {
        H2b[(size_t)(m0 + q * 4 + reg) * HID + col] = f2bf(acc[reg]);
        ls[reg] = acc[reg] * as;
        ld[reg] = acc[reg] * ad2;
    }
    #pragma unroll
    for (int reg = 0; reg < 4; ++reg) {
        #pragma unroll
        for (int off = 8; off > 0; off >>= 1) {
            ls[reg] += __shfl_down(ls[reg], off, 16);
            ld[reg] += __shfl_down(ld[reg], off, 16);
        }
    }
    __shared__ float Ls[4][16], Ld[4][16];
    if (r == 0) {
        #pragma unroll
        for (int reg = 0; reg < 4; ++reg) {
            Ls[w][q * 4 + reg] = ls[reg];
            Ld[w][q * 4 + reg] = ld[reg];
        }
    }
    __syncthreads();
    if (threadIdx.x < 16) {
        const int row = threadIdx.x;
        al_s2[m0 + row] = Ls[0][row] + Ls[1][row] + Ls[2][row] + Ls[3][row];
        al_d2[m0 + row] = Ld[0][row] + Ld[1][row] + Ld[2][row] + Ld[3][row];
    }
}

// ---------------------------------------------------------------------------
// Layer-2 aggregation, CSR gather (H=1), round-10 form (writes out2; the
// atomic-pool fusion of round 12 serialized on ~100-way address contention).
// 4 dsts/block, quarter-wave x2 unroll, 8 edges in flight.
// ---------------------------------------------------------------------------
__global__ __launch_bounds__(256) void agg2_csr(
    const int* __restrict__ rowptr, const int* __restrict__ csr_src,
    const float* __restrict__ al_s2, const float* __restrict__ al_d2,
    const uint2* __restrict__ H2b2, float* __restrict__ out2)
{
    const int dst = blockIdx.x * 4 + (threadIdx.x >> 6);
    const int l = threadIdx.x & 63;
    const int qt = l >> 4, j = l & 15;
    const int beg = rowptr[dst], end = rowptr[dst + 1];
    const float ad = al_d2[dst];
    float a0 = 0.f, a1 = 0.f, a2 = 0.f, a3 = 0.f, den = 0.f;
    for (int base = beg; base < end; base += 64) {
        const int n = min(64, end - base);
        int s_reg = 0;
        float w_reg = 0.f;
        if (l < n) {
            s_reg = csr_src[base + l];
            float t = al_s2[s_reg] + ad;
            t = t > 0.f ? t : NEG_SLOPE * t;
            w_reg = __expf(t);
        }
        const int n8 = (n + 7) & ~7;            // padded: w=0, s=0
        for (int i = 0; i < n8; i += 8) {
            const int e0 = i + qt, e1 = i + 4 + qt;
            const int   src0 = __shfl(s_reg, e0, 64), src1 = __shfl(s_reg, e1, 64);
            const float wt0  = __shfl(w_reg, e0, 64), wt1  = __shfl(w_reg, e1, 64);
            const uint2 u0 = H2b2[(size_t)src0 * (HID / 4) + j];
            const uint2 u1 = H2b2[(size_t)src1 * (HID / 4) + j];
            a0 += wt0 * bf_lo(u0.x) + wt1 * bf_lo(u1.x);
            a1 += wt0 * bf_hi(u0.x) + wt1 * bf_hi(u1.x);
            a2 += wt0 * bf_lo(u0.y) + wt1 * bf_lo(u1.y);
            a3 += wt0 * bf_hi(u0.y) + wt1 * bf_hi(u1.y);
            den += wt0 + wt1;
        }
    }
    #pragma unroll
    for (int m = 16; m <= 32; m <<= 1) {        // combine 4 edge subsets
        a0 += __shfl_xor(a0, m, 64);
        a1 += __shfl_xor(a1, m, 64);
        a2 += __shfl_xor(a2, m, 64);
        a3 += __shfl_xor(a3, m, 64);
        den += __shfl_xor(den, m, 64);
    }
    if (l < 16) {
        const float rcp = 1.f / (den + 1e-16f);
        *(float4*)(out2 + (size_t)dst * HID + 4 * j) =
            make_float4(a0 * rcp, a1 * rcp, a2 * rcp, a3 * rcp);
    }
}

// ---------------------------------------------------------------------------
// Pool (sorted-batch binary search) + FC + log_softmax. b2 folded as count*b2.
// ---------------------------------------------------------------------------
__global__ __launch_bounds__(64) void pool_fc_kernel(
    const float* __restrict__ out2, const float* __restrict__ b2,
    const int* __restrict__ batch,
    const float* __restrict__ fc_w, const float* __restrict__ fc_b,
    float* __restrict__ out)
{
    const int g = blockIdx.x;
    const int c = threadIdx.x;
    __shared__ int se[2];
    if (c < 2) {
        const int target = g + c;  // lower_bound(batch, target)
        int lo = 0, hi = N_NODES;
        while (lo < hi) { int mid = (lo + hi) >> 1; if (batch[mid] < target) lo = mid + 1; else hi = mid; }
        se[c] = lo;
    }
    __syncthreads();
    const int start = se[0], end = se[1];
    float acc = 0.f;
    for (int n = start; n < end; ++n)
        acc += out2[(size_t)n * HID + c];
    acc += (float)(end - start) * b2[c];
    __shared__ float pooled[HID];
    pooled[c] = acc;
    __syncthreads();
    __shared__ float logits[OUT_CH];
    if (c < OUT_CH) {
        float l = fc_b[c];
        #pragma unroll
        for (int k = 0; k < HID; ++k) l += pooled[k] * fc_w[k * OUT_CH + c];
        logits[c] = l;
    }
    __syncthreads();
    if (c == 0) {
        float m = logits[0];
        #pragma unroll
        for (int j2 = 1; j2 < OUT_CH; ++j2) m = fmaxf(m, logits[j2]);
        float s = 0.f;
        #pragma unroll
        for (int j2 = 0; j2 < OUT_CH; ++j2) s += __expf(logits[j2] - m);
        const float lse = m + __logf(s);
        #pragma unroll
        for (int j2 = 0; j2 < OUT_CH; ++j2) out[g * OUT_CH + j2] = logits[j2] - lse;
    }
}

// ---------------------------------------------------------------------------
// Workspace ≈ 53 MB
// ---------------------------------------------------------------------------

extern "C" void kernel_launch(void* const* d_in, const int* in_sizes, int n_in,
                              void* d_out, int out_size, void* d_ws, size_t ws_size,
                              hipStream_t stream)
{
    const float* x      = (const float*)d_in[0];
    const int*   ei     = (const int*)  d_in[1];   // [2, 800000] flat: src row, dst row
    const int*   batch  = (const int*)  d_in[2];
    const float* W1     = (const float*)d_in[3];
    const float* a_src1 = (const float*)d_in[4];
    const float* a_dst1 = (const float*)d_in[5];
    const float* b1     = (const float*)d_in[6];
    const float* W2     = (const float*)d_in[7];
    const float* a_src2 = (const float*)d_in[8];
    const float* a_dst2 = (const float*)d_in[9];
    const float* b2     = (const float*)d_in[10];
    const float* fc_w   = (const float*)d_in[11];
    const float* fc_b   = (const float*)d_in[12];
    float* out = (float*)d_out;

    char* ws = (char*)d_ws;
    size_t off = 0;
    auto alloc_b = [&](size_t bytes) { void* p = (void*)(ws + off); off += (bytes + 15) & ~15ull; return p; };

    unsigned short* H1b  = (unsigned short*)alloc_b((size_t)N_NODES * F1 * 2);     // 25.6 MB
    float* al_s1  = (float*)alloc_b((size_t)N_NODES * HEADS * 4);
    float* al_d1  = (float*)alloc_b((size_t)N_NODES * HEADS * 4);
    unsigned short* H2b  = (unsigned short*)alloc_b((size_t)N_NODES * HID * 2);    // 6.4 MB
    float* al_s2  = (float*)alloc_b((size_t)N_NODES * 4);
    float* al_d2  = (float*)alloc_b((size_t)N_NODES * 4);
    float* out2   = (float*)alloc_b((size_t)N_NODES * HID * 4);                    // 12.8 MB
    int*   deg    = (int*)alloc_b((size_t)N_NODES * 4);
    int*   rowptr = (int*)alloc_b((size_t)(N_NODES + 1) * 4);
    int*   cursor = (int*)alloc_b((size_t)N_NODES * 4);
    int*   csr_src= (int*)alloc_b((size_t)EP * 4);                                 // 3.4 MB
    int*   blocksum = (int*)alloc_b((size_t)SCAN_B * 4);
    unsigned short* W1p = (unsigned short*)alloc_b((size_t)IN_CH * F1 * 2);        // 64 KB
    unsigned short* W2p = (unsigned short*)alloc_b((size_t)F1 * HID * 2);          // 32 KB

    hipMemsetAsync(deg, 0, sizeof(int) * N_NODES, stream);

    // CSR build + W pack
    csr_count_packw<<<(EP + 255) / 256, 256, 0, stream>>>(ei, deg, W1, W1p, W2, W2p);
    csr_scan1  <<<SCAN_B, 256, 0, stream>>>(deg, blocksum);
    csr_scan2  <<<SCAN_B, 256, 0, stream>>>(deg, blocksum, rowptr, cursor);
    csr_scatter<<<(EP + 255) / 256, 256, 0, stream>>>(ei, cursor, csr_src);

    // Layer 1 GEMM (+ layer-1 logits)
    gemm1_mfma<<<N_NODES / 16, 256, 0, stream>>>(x, (const short*)W1p,
                                                 a_src1, a_dst1, H1b, al_s1, al_d1);

    // Fused: layer-1 aggregation -> (LDS) -> GEMM2 (+ layer-2 logits)
    agg1_gemm2<<<N_NODES / 16, 256, 0, stream>>>(rowptr, csr_src, al_s1, al_d1,
                                                 (const uint2*)H1b, b1,
                                                 (const short*)W2p, a_src2, a_dst2,
                                                 H2b, al_s2, al_d2);

    // Layer-2 aggregation (writes out2)
    agg2_csr<<<N_NODES / 4, 256, 0, stream>>>(rowptr, csr_src, al_s2, al_d2,
                                              (const uint2*)H2b, out2);

    // Readout
    pool_fc_kernel<<<NUM_GRAPHS, 64, 0, stream>>>(out2, b2, batch, fc_w, fc_b, out);
}